// Round 5
// baseline (550.965 us; speedup 1.0000x reference)
//
#include <hip/hip_runtime.h>
#include <hip/hip_bf16.h>
#include <hip/hip_cooperative_groups.h>

namespace cg = cooperative_groups;

typedef unsigned short u16;
typedef __bf16 bf16x8 __attribute__((ext_vector_type(8)));
typedef float f32x4 __attribute__((ext_vector_type(4)));

__device__ __forceinline__ u16 f2bf(float f) {
    unsigned u = __builtin_bit_cast(unsigned, f);
    unsigned r = (u + 0x7fffu + ((u >> 16) & 1u)) >> 16;
    return (u16)r;
}

#define GLDS16(g, l)                                                      \
    __builtin_amdgcn_global_load_lds(                                     \
        (const __attribute__((address_space(1))) void*)(g),               \
        (__attribute__((address_space(3))) void*)(l), 16, 0, 0)

union SMem {
    struct { u16 sA[128 * 32]; u16 sB[128 * 32]; } g;   // 16 KB gemm staging
    float tp[2][32][33];                                // 8.25 KB transpose tiles
};

// bf16 GEMM tile: 128x128 f32 tile at (by,bx) = A(M x KTOT) * Bt(N x KTOT)^T over
// K slice [kbase, kbase+KC). 8 waves (2x4), per-wave 64x32, BK=32.
template <int N, int KTOT, int KC>
__device__ __forceinline__ void gemm_stage(const u16* __restrict__ A,
                                           const u16* __restrict__ Bt,
                                           float* __restrict__ Cp,
                                           int kbase, int by, int bx, SMem& sm) {
    const int t = threadIdx.x;
    const int lane = t & 63;
    const int w = t >> 6;                 // 0..7
    const int wr = w >> 2, wc = w & 3;
    const int l15 = lane & 15, l4 = lane >> 4;
    const int row0 = by * 128, col0 = bx * 128;

    f32x4 acc[4][2] = {};
    const int sr = t >> 2;                // 0..127
    const int sk = (t & 3) * 8;

    for (int kt = 0; kt < KC / 32; ++kt) {
        const int k0 = kbase + (kt << 5);
        GLDS16(A  + (size_t)(row0 + sr) * KTOT + k0 + sk, sm.g.sA + t * 8);
        GLDS16(Bt + (size_t)(col0 + sr) * KTOT + k0 + sk, sm.g.sB + t * 8);
        __syncthreads();

        bf16x8 af[4], bfr[2];
#pragma unroll
        for (int m = 0; m < 4; ++m)
            af[m] = *(const bf16x8*)&sm.g.sA[(wr * 64 + m * 16 + l15) * 32 + l4 * 8];
#pragma unroll
        for (int n = 0; n < 2; ++n)
            bfr[n] = *(const bf16x8*)&sm.g.sB[(wc * 32 + n * 16 + l15) * 32 + l4 * 8];
#pragma unroll
        for (int m = 0; m < 4; ++m)
#pragma unroll
            for (int n = 0; n < 2; ++n)
                acc[m][n] = __builtin_amdgcn_mfma_f32_16x16x32_bf16(af[m], bfr[n], acc[m][n], 0, 0, 0);
        __syncthreads();
    }

    // D row = (lane>>4)*4 + j, col = lane&15  [verified layout]; f32 out
#pragma unroll
    for (int m = 0; m < 4; ++m)
#pragma unroll
        for (int n = 0; n < 2; ++n) {
            int r = row0 + wr * 64 + m * 16 + l4 * 4;
            int c = col0 + wc * 32 + n * 16 + l15;
#pragma unroll
            for (int j = 0; j < 4; ++j)
                Cp[(size_t)(r + j) * N + c] = acc[m][n][j];
        }
}

// ===================== cooperative mono-kernel =====================
// dims: x(4096,1024) V0(1024,2048) V1(2048,2048) V2(2048,1024)
// out = x @ ((V0@V1)@V2):
//   P1  = V0@V1        (1024x2048), split-K 4x512, f32 partials
//   P2t = V2^T @ P1^T  (1024x1024 == (P1@V2)^T), split-K 8x256
//   G   = x @ P2       (4096x1024 f32), split-K 2x512
__global__ __launch_bounds__(512, 4) void bipcn_mono(const float* __restrict__ x,
                                                     const float* __restrict__ V0,
                                                     const float* __restrict__ V1,
                                                     const float* __restrict__ V2,
                                                     float* __restrict__ out,
                                                     char* __restrict__ ws) {
    __shared__ SMem sm;
    cg::grid_group grid = cg::this_grid();

    u16* xb  = (u16*)(ws);                         // 8 MB (4096x1024)
    u16* V0b = (u16*)(ws + ((size_t)8 << 20));     // 4 MB (1024x2048)
    u16* V1t = (u16*)(ws + ((size_t)12 << 20));    // 8 MB (2048x2048 = V1^T)
    u16* V2t = (u16*)(ws + ((size_t)20 << 20));    // 4 MB (1024x2048 = V2^T)
    u16* P1  = (u16*)(ws + ((size_t)24 << 20));    // 4 MB (1024x2048)
    u16* P2t = (u16*)(ws + ((size_t)28 << 20));    // 2 MB (1024x1024)
    float* pf = (float*)(ws + ((size_t)32 << 20)); // 32 MB f32 split-K partials

    const int b = blockIdx.x, t = threadIdx.x;
    const int tid = b * 512 + t;
    const int NT = 512 * 512;

    // stage 0: prep (convert x,V0; transpose V1,V2)
    for (int i = tid; i < 4096 * 1024 / 4; i += NT) {
        float4 v = ((const float4*)x)[i];
        ushort4 o; o.x = f2bf(v.x); o.y = f2bf(v.y); o.z = f2bf(v.z); o.w = f2bf(v.w);
        ((ushort4*)xb)[i] = o;
    }
    for (int i = tid; i < 1024 * 2048 / 4; i += NT) {
        float4 v = ((const float4*)V0)[i];
        ushort4 o; o.x = f2bf(v.x); o.y = f2bf(v.y); o.z = f2bf(v.z); o.w = f2bf(v.w);
        ((ushort4*)V0b)[i] = o;
    }
    {
        int slot = t >> 8, tt = t & 255, tx = tt & 31, ty = tt >> 5;
        for (int tile = b * 2 + slot; tile < 6144; tile += 1024) {
            const float* src; u16* dst; int C, rt, ct;
            if (tile < 4096) { src = V1; dst = V1t; C = 2048; rt = tile >> 6; ct = tile & 63; }
            else { int t2 = tile - 4096; src = V2; dst = V2t; C = 1024; rt = t2 >> 5; ct = t2 & 31; }
            int r0 = rt * 32, c0 = ct * 32;
            for (int i = ty; i < 32; i += 8)
                sm.tp[slot][i][tx] = src[(size_t)(r0 + i) * C + (c0 + tx)];
            __syncthreads();
            for (int j = ty; j < 32; j += 8)
                dst[(size_t)(c0 + j) * 2048 + (r0 + tx)] = f2bf(sm.tp[slot][tx][j]);
            __syncthreads();
        }
    }
    grid.sync();

    // stage 1: P1 partials = V0 @ V1, split-K 4x512
    {
        int z = b >> 7, tile = b & 127;
        gemm_stage<2048, 2048, 512>(V0b, V1t, pf + (size_t)z * 1024 * 2048,
                                    z * 512, tile >> 4, tile & 15, sm);
    }
    grid.sync();

    // stage 2: reduce 4 -> P1 (bf16)
    {
        const float4* p4 = (const float4*)pf;
        for (int i = tid; i < 1024 * 2048 / 4; i += NT) {
            float4 s = p4[i];
            float4 a = p4[i + 524288], c = p4[i + 2 * 524288], d = p4[i + 3 * 524288];
            s.x += a.x + c.x + d.x; s.y += a.y + c.y + d.y;
            s.z += a.z + c.z + d.z; s.w += a.w + c.w + d.w;
            ushort4 o; o.x = f2bf(s.x); o.y = f2bf(s.y); o.z = f2bf(s.z); o.w = f2bf(s.w);
            ((ushort4*)P1)[i] = o;
        }
    }
    grid.sync();

    // stage 3: P2t partials = V2^T @ P1^T, split-K 8x256
    {
        int z = b >> 6, tile = b & 63;
        gemm_stage<1024, 2048, 256>(V2t, P1, pf + (size_t)z * 1024 * 1024,
                                    z * 256, tile >> 3, tile & 7, sm);
    }
    grid.sync();

    // stage 4: reduce 8 -> P2t (bf16)
    {
        const float4* p4 = (const float4*)pf;
        for (int i = tid; i < 1024 * 1024 / 4; i += NT) {
            float sx = 0, sy = 0, sz = 0, sw = 0;
#pragma unroll
            for (int zz = 0; zz < 8; ++zz) {
                float4 v = p4[i + zz * 262144];
                sx += v.x; sy += v.y; sz += v.z; sw += v.w;
            }
            ushort4 o; o.x = f2bf(sx); o.y = f2bf(sy); o.z = f2bf(sz); o.w = f2bf(sw);
            ((ushort4*)P2t)[i] = o;
        }
    }
    grid.sync();

    // stage 5: G partials = x @ P2, split-K 2x512
    {
        int z = b >> 8, tile = b & 255;
        gemm_stage<1024, 1024, 512>(xb, P2t, pf + (size_t)z * 4096 * 1024,
                                    z * 512, tile >> 3, tile & 7, sm);
    }
    grid.sync();

    // stage 6: reduce 2 -> out (f32)
    {
        const float4* p4 = (const float4*)pf;
        float4* o4 = (float4*)out;
        for (int i = tid; i < 4096 * 1024 / 4; i += NT) {
            float4 s = p4[i], c = p4[i + 1048576];
            s.x += c.x; s.y += c.y; s.z += c.z; s.w += c.w;
            o4[i] = s;
        }
    }
}

// ===================== fallback multi-kernel path (round-2 proven, 88 µs) =====
__global__ __launch_bounds__(256) void prep_convert(const float* __restrict__ x,
                                                    u16* __restrict__ xb,
                                                    const float* __restrict__ V0,
                                                    u16* __restrict__ V0b) {
    const int NX = 4096 * 1024 / 4;
    const int NV = 1024 * 2048 / 4;
    int i = blockIdx.x * 256 + threadIdx.x;
    const float* src; u16* dst; int j;
    if (i < NX) { src = x; dst = xb; j = i; }
    else { j = i - NX; if (j >= NV) return; src = V0; dst = V0b; }
    float4 v = ((const float4*)src)[j];
    ushort4 o; o.x = f2bf(v.x); o.y = f2bf(v.y); o.z = f2bf(v.z); o.w = f2bf(v.w);
    ((ushort4*)dst)[j] = o;
}

__global__ __launch_bounds__(256) void prep_transpose(const float* __restrict__ V1,
                                                      u16* __restrict__ V1t,
                                                      const float* __restrict__ V2,
                                                      u16* __restrict__ V2t) {
    __shared__ float tile[32][33];
    const float* src; u16* dst;
    int R, C, rt = blockIdx.y, ct = blockIdx.x;
    if (rt < 64) { src = V1; dst = V1t; R = 2048; C = 2048; }
    else { rt -= 64; src = V2; dst = V2t; R = 2048; C = 1024; if (ct >= 32) return; }
    int r0 = rt * 32, c0 = ct * 32;
    int tx = threadIdx.x, ty = threadIdx.y;
    for (int i = ty; i < 32; i += 8)
        tile[i][tx] = src[(size_t)(r0 + i) * C + (c0 + tx)];
    __syncthreads();
    for (int j = ty; j < 32; j += 8)
        dst[(size_t)(c0 + j) * R + (r0 + tx)] = f2bf(tile[tx][j]);
}

__global__ __launch_bounds__(512) void gemm_bt(const u16* __restrict__ A,
                                               const u16* __restrict__ Bt,
                                               u16* __restrict__ Cpart,
                                               int M, int N, int Ktot, int Kc) {
    __shared__ u16 sA[128 * 32];
    __shared__ u16 sB[128 * 32];
    const int t = threadIdx.x;
    const int lane = t & 63;
    const int w = t >> 6;
    const int wr = w >> 2, wc = w & 3;
    const int l15 = lane & 15, l4 = lane >> 4;
    const int row0 = blockIdx.y * 128, col0 = blockIdx.x * 128;
    const int kbase = blockIdx.z * Kc;

    f32x4 acc[4][2] = {};
    const int sr = t >> 2;
    const int sk = (t & 3) * 8;

    const int nK = Kc >> 5;
    for (int kt = 0; kt < nK; ++kt) {
        const int k0 = kbase + (kt << 5);
        GLDS16(A  + (size_t)(row0 + sr) * Ktot + k0 + sk, sA + t * 8);
        GLDS16(Bt + (size_t)(col0 + sr) * Ktot + k0 + sk, sB + t * 8);
        __syncthreads();

        bf16x8 af[4], bfr[2];
#pragma unroll
        for (int m = 0; m < 4; ++m)
            af[m] = *(const bf16x8*)&sA[(wr * 64 + m * 16 + l15) * 32 + l4 * 8];
#pragma unroll
        for (int n = 0; n < 2; ++n)
            bfr[n] = *(const bf16x8*)&sB[(wc * 32 + n * 16 + l15) * 32 + l4 * 8];
#pragma unroll
        for (int m = 0; m < 4; ++m)
#pragma unroll
            for (int n = 0; n < 2; ++n)
                acc[m][n] = __builtin_amdgcn_mfma_f32_16x16x32_bf16(af[m], bfr[n], acc[m][n], 0, 0, 0);
        __syncthreads();
    }

    const size_t zoff = (size_t)blockIdx.z * M * N;
#pragma unroll
    for (int m = 0; m < 4; ++m)
#pragma unroll
        for (int n = 0; n < 2; ++n) {
            int r = row0 + wr * 64 + m * 16 + l4 * 4;
            int c = col0 + wc * 32 + n * 16 + l15;
#pragma unroll
            for (int j = 0; j < 4; ++j)
                Cpart[zoff + (size_t)(r + j) * N + c] = f2bf(acc[m][n][j]);
        }
}

template <int KS, int F32OUT>
__global__ __launch_bounds__(256) void reduce_parts(const u16* __restrict__ part,
                                                    void* __restrict__ out, int mn) {
    int i = blockIdx.x * 256 + threadIdx.x;
    int n8 = mn >> 3;
    if (i >= n8) return;
    float s[8] = {0, 0, 0, 0, 0, 0, 0, 0};
#pragma unroll
    for (int z = 0; z < KS; ++z) {
        uint4 v = ((const uint4*)(part + (size_t)z * mn))[i];
        unsigned a0 = v.x, a1 = v.y, a2 = v.z, a3 = v.w;
        s[0] += __builtin_bit_cast(float, a0 << 16);
        s[1] += __builtin_bit_cast(float, a0 & 0xffff0000u);
        s[2] += __builtin_bit_cast(float, a1 << 16);
        s[3] += __builtin_bit_cast(float, a1 & 0xffff0000u);
        s[4] += __builtin_bit_cast(float, a2 << 16);
        s[5] += __builtin_bit_cast(float, a2 & 0xffff0000u);
        s[6] += __builtin_bit_cast(float, a3 << 16);
        s[7] += __builtin_bit_cast(float, a3 & 0xffff0000u);
    }
    if (F32OUT) {
        float4 o0 = {s[0], s[1], s[2], s[3]};
        float4 o1 = {s[4], s[5], s[6], s[7]};
        ((float4*)out)[2 * i] = o0;
        ((float4*)out)[2 * i + 1] = o1;
    } else {
        uint4 o;
        o.x = (unsigned)f2bf(s[0]) | ((unsigned)f2bf(s[1]) << 16);
        o.y = (unsigned)f2bf(s[2]) | ((unsigned)f2bf(s[3]) << 16);
        o.z = (unsigned)f2bf(s[4]) | ((unsigned)f2bf(s[5]) << 16);
        o.w = (unsigned)f2bf(s[6]) | ((unsigned)f2bf(s[7]) << 16);
        ((uint4*)out)[i] = o;
    }
}

// d_in order: x, V0, W0, V1, W1, V2, W2
extern "C" void kernel_launch(void* const* d_in, const int* in_sizes, int n_in,
                              void* d_out, int out_size, void* d_ws, size_t ws_size,
                              hipStream_t stream) {
    const float* x  = (const float*)d_in[0];
    const float* V0 = (const float*)d_in[1];
    const float* V1 = (const float*)d_in[3];
    const float* V2 = (const float*)d_in[5];
    float* out = (float*)d_out;
    char* ws = (char*)d_ws;

    // try the cooperative mono-kernel first
    {
        const float *ax = x, *a0 = V0, *a1 = V1, *a2 = V2;
        float* ao = out;
        char* aw = ws;
        void* args[] = { &ax, &a0, &a1, &a2, &ao, &aw };
        hipError_t e = hipLaunchCooperativeKernel(bipcn_mono, dim3(512), dim3(512),
                                                  args, 0u, stream);
        if (e == hipSuccess) return;
        (void)hipGetLastError();   // clear sticky error, fall through
    }

    // fallback: proven multi-kernel path
    u16* xb   = (u16*)(ws);
    u16* V0b  = (u16*)(ws + ((size_t)8 << 20));
    u16* V1t  = (u16*)(ws + ((size_t)12 << 20));
    u16* V2t  = (u16*)(ws + ((size_t)20 << 20));
    u16* P1   = (u16*)(ws + ((size_t)24 << 20));
    u16* P2t  = (u16*)(ws + ((size_t)28 << 20));
    u16* part = (u16*)(ws + ((size_t)32 << 20));

    prep_convert<<<6144, 256, 0, stream>>>(x, xb, V0, V0b);
    prep_transpose<<<dim3(64, 128), dim3(32, 8), 0, stream>>>(V1, V1t, V2, V2t);

    gemm_bt<<<dim3(16, 8, 4), 512, 0, stream>>>(V0b, V1t, part, 1024, 2048, 2048, 512);
    reduce_parts<4, 0><<<1024, 256, 0, stream>>>(part, P1, 1024 * 2048);

    gemm_bt<<<dim3(8, 8, 8), 512, 0, stream>>>(V2t, P1, part, 1024, 1024, 2048, 256);
    reduce_parts<8, 0><<<512, 256, 0, stream>>>(part, P2t, 1024 * 1024);

    gemm_bt<<<dim3(8, 32, 2), 512, 0, stream>>>(xb, P2t, part, 4096, 1024, 1024, 512);
    reduce_parts<2, 1><<<2048, 256, 0, stream>>>(part, d_out, 4096 * 1024);
}

// Round 6
// 93.362 us; speedup vs baseline: 5.9014x; 5.9014x over previous
//
#include <hip/hip_runtime.h>
#include <hip/hip_bf16.h>

typedef unsigned short u16;
typedef __bf16 bf16x8 __attribute__((ext_vector_type(8)));
typedef float f32x4 __attribute__((ext_vector_type(4)));

__device__ __forceinline__ u16 f2bf(float f) {
    unsigned u = __builtin_bit_cast(unsigned, f);
    unsigned r = (u + 0x7fffu + ((u >> 16) & 1u)) >> 16;
    return (u16)r;
}

#define GLDS16(g, l)                                                      \
    __builtin_amdgcn_global_load_lds(                                     \
        (const __attribute__((address_space(1))) void*)(g),               \
        (__attribute__((address_space(3))) void*)(l), 16, 0, 0)

// ---- fused prep: convert x (4096x1024) + V0 (1024x2048) to bf16;
// ---- transpose+convert V1 (2048x2048) -> V1t, V2 (2048x1024) -> V2t
__global__ __launch_bounds__(256) void prep_all(const float* __restrict__ x,
                                                u16* __restrict__ xb,
                                                const float* __restrict__ V0,
                                                u16* __restrict__ V0b,
                                                const float* __restrict__ V1,
                                                u16* __restrict__ V1t,
                                                const float* __restrict__ V2,
                                                u16* __restrict__ V2t) {
    __shared__ float tile[32][33];
    const int b = blockIdx.x, t = threadIdx.x;
    if (b < 1024) {
        // x: 1048576 float4s, 1024 blocks
        for (int i = b * 256 + t; i < 4096 * 1024 / 4; i += 1024 * 256) {
            float4 v = ((const float4*)x)[i];
            ushort4 o; o.x = f2bf(v.x); o.y = f2bf(v.y); o.z = f2bf(v.z); o.w = f2bf(v.w);
            ((ushort4*)xb)[i] = o;
        }
    } else if (b < 1536) {
        // V0: 524288 float4s, 512 blocks
        for (int i = (b - 1024) * 256 + t; i < 1024 * 2048 / 4; i += 512 * 256) {
            float4 v = ((const float4*)V0)[i];
            ushort4 o; o.x = f2bf(v.x); o.y = f2bf(v.y); o.z = f2bf(v.z); o.w = f2bf(v.w);
            ((ushort4*)V0b)[i] = o;
        }
    } else {
        // transposes: 4096 V1 tiles + 2048 V2 tiles, 512 blocks x 12 tiles
        const int bb = b - 1536;
        const int tx = t & 31, ty = t >> 5;
        for (int tl = bb; tl < 6144; tl += 512) {
            const float* src; u16* dst; int C, rt, ct;
            if (tl < 4096) { src = V1; dst = V1t; C = 2048; rt = tl >> 6; ct = tl & 63; }
            else { int t2 = tl - 4096; src = V2; dst = V2t; C = 1024; rt = t2 >> 5; ct = t2 & 31; }
            int r0 = rt * 32, c0 = ct * 32;
            for (int i = ty; i < 32; i += 8)
                tile[i][tx] = src[(size_t)(r0 + i) * C + (c0 + tx)];
            __syncthreads();
            for (int j = ty; j < 32; j += 8)
                dst[(size_t)(c0 + j) * 2048 + (r0 + tx)] = f2bf(tile[tx][j]);
            __syncthreads();
        }
    }
}

// ---------------- bf16 GEMM: Cpart(z) = A(M x Kc slice) * Bt(N x Kc slice)^T --
// 128x128 tile, BK=32, 8 waves (2x4), per-wave 64x32, double-buffered LDS with
// one vmcnt(0)+s_barrier per K-step (stage t+1 issued before compute of t).
__global__ __launch_bounds__(512) void gemm_bt(const u16* __restrict__ A,
                                               const u16* __restrict__ Bt,
                                               u16* __restrict__ Cpart,
                                               int M, int N, int Ktot, int Kc) {
    __shared__ u16 sA[2][128 * 32];
    __shared__ u16 sB[2][128 * 32];

    const int t = threadIdx.x;
    const int lane = t & 63;
    const int w = t >> 6;             // 0..7
    const int wr = w >> 2, wc = w & 3;
    const int l15 = lane & 15, l4 = lane >> 4;
    const int row0 = blockIdx.y * 128, col0 = blockIdx.x * 128;
    const int kbase = blockIdx.z * Kc;

    f32x4 acc[4][2] = {};

    // staging: thread t -> row t>>2, k-chunk (t&3)*8; dest lane-linear t*16B
    const int sr = t >> 2;
    const int sk = (t & 3) * 8;
    const u16* Ab = A  + (size_t)(row0 + sr) * Ktot + kbase + sk;
    const u16* Bb = Bt + (size_t)(col0 + sr) * Ktot + kbase + sk;

    // prologue: stage K-tile 0 into buffer 0
    GLDS16(Ab, &sA[0][t * 8]);
    GLDS16(Bb, &sB[0][t * 8]);
    asm volatile("s_waitcnt vmcnt(0)" ::: "memory");
    __builtin_amdgcn_s_barrier();

    const int nK = Kc >> 5;
    int cur = 0;
    for (int kt = 0; kt < nK; ++kt) {
        // issue next tile's staging into the other buffer (hides under MFMA)
        if (kt + 1 < nK) {
            GLDS16(Ab + (kt + 1) * 32, &sA[cur ^ 1][t * 8]);
            GLDS16(Bb + (kt + 1) * 32, &sB[cur ^ 1][t * 8]);
        }

        bf16x8 af[4], bfr[2];
#pragma unroll
        for (int m = 0; m < 4; ++m)
            af[m] = *(const bf16x8*)&sA[cur][(wr * 64 + m * 16 + l15) * 32 + l4 * 8];
#pragma unroll
        for (int n = 0; n < 2; ++n)
            bfr[n] = *(const bf16x8*)&sB[cur][(wc * 32 + n * 16 + l15) * 32 + l4 * 8];
#pragma unroll
        for (int m = 0; m < 4; ++m)
#pragma unroll
            for (int n = 0; n < 2; ++n)
                acc[m][n] = __builtin_amdgcn_mfma_f32_16x16x32_bf16(af[m], bfr[n], acc[m][n], 0, 0, 0);

        // next-tile loads landed + all waves done reading cur before overwrite
        asm volatile("s_waitcnt vmcnt(0)" ::: "memory");
        __builtin_amdgcn_s_barrier();
        cur ^= 1;
    }

    // epilogue: D row = (lane>>4)*4 + j, col = lane&15  [verified layout]
    const size_t zoff = (size_t)blockIdx.z * M * N;
#pragma unroll
    for (int m = 0; m < 4; ++m)
#pragma unroll
        for (int n = 0; n < 2; ++n) {
            int r = row0 + wr * 64 + m * 16 + l4 * 4;
            int c = col0 + wc * 32 + n * 16 + l15;
#pragma unroll
            for (int j = 0; j < 4; ++j)
                Cpart[zoff + (size_t)(r + j) * N + c] = f2bf(acc[m][n][j]);
        }
}

// -------- sum KS bf16 partial buffers -> bf16 or f32 output (8 elems/thread) --
template <int KS, int F32OUT>
__global__ __launch_bounds__(256) void reduce_parts(const u16* __restrict__ part,
                                                    void* __restrict__ out, int mn) {
    int i = blockIdx.x * 256 + threadIdx.x;
    int n8 = mn >> 3;
    if (i >= n8) return;
    float s[8] = {0, 0, 0, 0, 0, 0, 0, 0};
#pragma unroll
    for (int z = 0; z < KS; ++z) {
        uint4 v = ((const uint4*)(part + (size_t)z * mn))[i];
        unsigned a0 = v.x, a1 = v.y, a2 = v.z, a3 = v.w;
        s[0] += __builtin_bit_cast(float, a0 << 16);
        s[1] += __builtin_bit_cast(float, a0 & 0xffff0000u);
        s[2] += __builtin_bit_cast(float, a1 << 16);
        s[3] += __builtin_bit_cast(float, a1 & 0xffff0000u);
        s[4] += __builtin_bit_cast(float, a2 << 16);
        s[5] += __builtin_bit_cast(float, a2 & 0xffff0000u);
        s[6] += __builtin_bit_cast(float, a3 << 16);
        s[7] += __builtin_bit_cast(float, a3 & 0xffff0000u);
    }
    if (F32OUT) {
        float4 o0 = {s[0], s[1], s[2], s[3]};
        float4 o1 = {s[4], s[5], s[6], s[7]};
        ((float4*)out)[2 * i] = o0;
        ((float4*)out)[2 * i + 1] = o1;
    } else {
        uint4 o;
        o.x = (unsigned)f2bf(s[0]) | ((unsigned)f2bf(s[1]) << 16);
        o.y = (unsigned)f2bf(s[2]) | ((unsigned)f2bf(s[3]) << 16);
        o.z = (unsigned)f2bf(s[4]) | ((unsigned)f2bf(s[5]) << 16);
        o.w = (unsigned)f2bf(s[6]) | ((unsigned)f2bf(s[7]) << 16);
        ((uint4*)out)[i] = o;
    }
}

// dims: x(4096,1024)  V0(1024,2048) V1(2048,2048) V2(2048,1024)
// out = x @ ((V0@V1)@V2):
//   P1  = V0@V1          (1024x2048 bf16), split-K 4x512
//   P2t = V2^T @ P1^T    (1024x1024 bf16 == (P1@V2)^T), split-K 8x256
//   G   = x @ P2         (4096x1024 f32 -> d_out), split-K 2x512
// d_in order: x, V0, W0, V1, W1, V2, W2
extern "C" void kernel_launch(void* const* d_in, const int* in_sizes, int n_in,
                              void* d_out, int out_size, void* d_ws, size_t ws_size,
                              hipStream_t stream) {
    const float* x  = (const float*)d_in[0];
    const float* V0 = (const float*)d_in[1];
    const float* V1 = (const float*)d_in[3];
    const float* V2 = (const float*)d_in[5];

    char* ws = (char*)d_ws;
    u16* xb   = (u16*)(ws);                          // 8 MB  (4096x1024)
    u16* V0b  = (u16*)(ws + ((size_t)8 << 20));      // 4 MB  (1024x2048, row-major)
    u16* V1t  = (u16*)(ws + ((size_t)12 << 20));     // 8 MB  (2048x2048, = V1^T)
    u16* V2t  = (u16*)(ws + ((size_t)20 << 20));     // 4 MB  (1024x2048, = V2^T)
    u16* P1   = (u16*)(ws + ((size_t)24 << 20));     // 4 MB  (1024x2048)
    u16* P2t  = (u16*)(ws + ((size_t)28 << 20));     // 2 MB  (1024x1024)
    u16* part = (u16*)(ws + ((size_t)30 << 20));     // 16 MB max (split-K partials)

    // fused prep
    prep_all<<<2048, 256, 0, stream>>>(x, xb, V0, V0b, V1, V1t, V2, V2t);

    // P1 = V0 @ V1 : M=1024, N=2048, K=2048, split-K 4x512
    gemm_bt<<<dim3(16, 8, 4), 512, 0, stream>>>(V0b, V1t, part, 1024, 2048, 2048, 512);
    reduce_parts<4, 0><<<1024, 256, 0, stream>>>(part, P1, 1024 * 2048);

    // P2t = V2^T @ P1^T : M=1024, N=1024, K=2048, split-K 8x256
    gemm_bt<<<dim3(8, 8, 8), 512, 0, stream>>>(V2t, P1, part, 1024, 1024, 2048, 256);
    reduce_parts<8, 0><<<512, 256, 0, stream>>>(part, P2t, 1024 * 1024);

    // G = x @ P2 : M=4096, N=1024, K=1024, split-K 2x512
    gemm_bt<<<dim3(8, 32, 2), 512, 0, stream>>>(xb, P2t, part, 4096, 1024, 1024, 512);
    reduce_parts<2, 1><<<2048, 256, 0, stream>>>(part, d_out, 4096 * 1024);
}

// Round 7
// 81.429 us; speedup vs baseline: 6.7662x; 1.1466x over previous
//
#include <hip/hip_runtime.h>
#include <hip/hip_bf16.h>

typedef unsigned short u16;
typedef __bf16 bf16x8 __attribute__((ext_vector_type(8)));
typedef float f32x4 __attribute__((ext_vector_type(4)));

__device__ __forceinline__ u16 f2bf(float f) {
    unsigned u = __builtin_bit_cast(unsigned, f);
    unsigned r = (u + 0x7fffu + ((u >> 16) & 1u)) >> 16;
    return (u16)r;
}

#define GLDS16(g, l)                                                      \
    __builtin_amdgcn_global_load_lds(                                     \
        (const __attribute__((address_space(1))) void*)(g),               \
        (__attribute__((address_space(3))) void*)(l), 16, 0, 0)

// ---- flat f32->bf16 convert of x (1048576 float4) + V0 (524288 float4) ----
// grid 3072 x 256, 2 float4 per thread, no loops/tails.
__global__ __launch_bounds__(256) void prep_convert(const float* __restrict__ x,
                                                    u16* __restrict__ xb,
                                                    const float* __restrict__ V0,
                                                    u16* __restrict__ V0b) {
    int i0 = blockIdx.x * 512 + threadIdx.x;
#pragma unroll
    for (int p = 0; p < 2; ++p) {
        int i = i0 + p * 256;
        const float* s; u16* d; int j;
        if (i < 1048576) { s = x; d = xb; j = i; }
        else { s = V0; d = V0b; j = i - 1048576; }
        float4 v = ((const float4*)s)[j];
        ushort4 o; o.x = f2bf(v.x); o.y = f2bf(v.y); o.z = f2bf(v.z); o.w = f2bf(v.w);
        ((ushort4*)d)[j] = o;
    }
}

// ---- 64x64-tile transpose+convert: V1 (2048x2048) -> V1t, V2 (2048x1024) -> V2t
// one tile per block (1024 + 512 = 1536 blocks), float4 loads, ushort4 stores.
__global__ __launch_bounds__(256) void prep_transpose(const float* __restrict__ V1,
                                                      u16* __restrict__ V1t,
                                                      const float* __restrict__ V2,
                                                      u16* __restrict__ V2t) {
    __shared__ float tile[64][65];
    const int b = blockIdx.x;
    const float* src; u16* dst; int C, rt, ct;
    if (b < 1024) { src = V1; dst = V1t; C = 2048; rt = b >> 5; ct = b & 31; }
    else { int b2 = b - 1024; src = V2; dst = V2t; C = 1024; rt = b2 >> 4; ct = b2 & 15; }
    const int r0 = rt * 64, c0 = ct * 64;
    const int t = threadIdx.x;
    const int trow = t >> 4;       // 0..15
    const int tc4 = t & 15;        // float4 / ushort4 chunk index

#pragma unroll
    for (int p = 0; p < 4; ++p) {
        int r = p * 16 + trow;
        float4 v = *(const float4*)&src[(size_t)(r0 + r) * C + c0 + tc4 * 4];
        tile[r][tc4 * 4 + 0] = v.x; tile[r][tc4 * 4 + 1] = v.y;
        tile[r][tc4 * 4 + 2] = v.z; tile[r][tc4 * 4 + 3] = v.w;
    }
    __syncthreads();
#pragma unroll
    for (int p = 0; p < 4; ++p) {
        int c = p * 16 + trow;         // source column = dst row offset
        int rr = tc4 * 4;              // 4 source rows -> 4 consecutive dst cols
        ushort4 o;
        o.x = f2bf(tile[rr + 0][c]); o.y = f2bf(tile[rr + 1][c]);
        o.z = f2bf(tile[rr + 2][c]); o.w = f2bf(tile[rr + 3][c]);
        *(ushort4*)&dst[(size_t)(c0 + c) * 2048 + r0 + rr] = o;
    }
}

// ---------------- bf16 GEMM: Cpart(z) = A(M x Kc slice) * Bt(N x Kc slice)^T --
// 128x128 tile, BK=32, 8 waves (2x4), per-wave 64x32, double-buffered LDS with
// one vmcnt(0)+s_barrier per K-step (stage t+1 issued before compute of t).
__global__ __launch_bounds__(512) void gemm_bt(const u16* __restrict__ A,
                                               const u16* __restrict__ Bt,
                                               u16* __restrict__ Cpart,
                                               int M, int N, int Ktot, int Kc) {
    __shared__ u16 sA[2][128 * 32];
    __shared__ u16 sB[2][128 * 32];

    const int t = threadIdx.x;
    const int lane = t & 63;
    const int w = t >> 6;             // 0..7
    const int wr = w >> 2, wc = w & 3;
    const int l15 = lane & 15, l4 = lane >> 4;
    const int row0 = blockIdx.y * 128, col0 = blockIdx.x * 128;
    const int kbase = blockIdx.z * Kc;

    f32x4 acc[4][2] = {};

    const int sr = t >> 2;
    const int sk = (t & 3) * 8;
    const u16* Ab = A  + (size_t)(row0 + sr) * Ktot + kbase + sk;
    const u16* Bb = Bt + (size_t)(col0 + sr) * Ktot + kbase + sk;

    GLDS16(Ab, &sA[0][t * 8]);
    GLDS16(Bb, &sB[0][t * 8]);
    asm volatile("s_waitcnt vmcnt(0)" ::: "memory");
    __builtin_amdgcn_s_barrier();

    const int nK = Kc >> 5;
    int cur = 0;
    for (int kt = 0; kt < nK; ++kt) {
        if (kt + 1 < nK) {
            GLDS16(Ab + (kt + 1) * 32, &sA[cur ^ 1][t * 8]);
            GLDS16(Bb + (kt + 1) * 32, &sB[cur ^ 1][t * 8]);
        }

        bf16x8 af[4], bfr[2];
#pragma unroll
        for (int m = 0; m < 4; ++m)
            af[m] = *(const bf16x8*)&sA[cur][(wr * 64 + m * 16 + l15) * 32 + l4 * 8];
#pragma unroll
        for (int n = 0; n < 2; ++n)
            bfr[n] = *(const bf16x8*)&sB[cur][(wc * 32 + n * 16 + l15) * 32 + l4 * 8];
#pragma unroll
        for (int m = 0; m < 4; ++m)
#pragma unroll
            for (int n = 0; n < 2; ++n)
                acc[m][n] = __builtin_amdgcn_mfma_f32_16x16x32_bf16(af[m], bfr[n], acc[m][n], 0, 0, 0);

        asm volatile("s_waitcnt vmcnt(0)" ::: "memory");
        __builtin_amdgcn_s_barrier();
        cur ^= 1;
    }

    const size_t zoff = (size_t)blockIdx.z * M * N;
#pragma unroll
    for (int m = 0; m < 4; ++m)
#pragma unroll
        for (int n = 0; n < 2; ++n) {
            int r = row0 + wr * 64 + m * 16 + l4 * 4;
            int c = col0 + wc * 32 + n * 16 + l15;
#pragma unroll
            for (int j = 0; j < 4; ++j)
                Cpart[zoff + (size_t)(r + j) * N + c] = f2bf(acc[m][n][j]);
        }
}

// -------- sum KS bf16 partial buffers -> bf16 or f32 output (8 elems/thread) --
template <int KS, int F32OUT>
__global__ __launch_bounds__(256) void reduce_parts(const u16* __restrict__ part,
                                                    void* __restrict__ out, int mn) {
    int i = blockIdx.x * 256 + threadIdx.x;
    int n8 = mn >> 3;
    if (i >= n8) return;
    float s[8] = {0, 0, 0, 0, 0, 0, 0, 0};
#pragma unroll
    for (int z = 0; z < KS; ++z) {
        uint4 v = ((const uint4*)(part + (size_t)z * mn))[i];
        unsigned a0 = v.x, a1 = v.y, a2 = v.z, a3 = v.w;
        s[0] += __builtin_bit_cast(float, a0 << 16);
        s[1] += __builtin_bit_cast(float, a0 & 0xffff0000u);
        s[2] += __builtin_bit_cast(float, a1 << 16);
        s[3] += __builtin_bit_cast(float, a1 & 0xffff0000u);
        s[4] += __builtin_bit_cast(float, a2 << 16);
        s[5] += __builtin_bit_cast(float, a2 & 0xffff0000u);
        s[6] += __builtin_bit_cast(float, a3 << 16);
        s[7] += __builtin_bit_cast(float, a3 & 0xffff0000u);
    }
    if (F32OUT) {
        float4 o0 = {s[0], s[1], s[2], s[3]};
        float4 o1 = {s[4], s[5], s[6], s[7]};
        ((float4*)out)[2 * i] = o0;
        ((float4*)out)[2 * i + 1] = o1;
    } else {
        uint4 o;
        o.x = (unsigned)f2bf(s[0]) | ((unsigned)f2bf(s[1]) << 16);
        o.y = (unsigned)f2bf(s[2]) | ((unsigned)f2bf(s[3]) << 16);
        o.z = (unsigned)f2bf(s[4]) | ((unsigned)f2bf(s[5]) << 16);
        o.w = (unsigned)f2bf(s[6]) | ((unsigned)f2bf(s[7]) << 16);
        ((uint4*)out)[i] = o;
    }
}

// dims: x(4096,1024)  V0(1024,2048) V1(2048,2048) V2(2048,1024)
// out = x @ ((V0@V1)@V2):
//   P1  = V0@V1          (1024x2048 bf16), split-K 4x512
//   P2t = V2^T @ P1^T    (1024x1024 bf16 == (P1@V2)^T), split-K 8x256
//   G   = x @ P2         (4096x1024 f32 -> d_out), split-K 2x512
// d_in order: x, V0, W0, V1, W1, V2, W2
extern "C" void kernel_launch(void* const* d_in, const int* in_sizes, int n_in,
                              void* d_out, int out_size, void* d_ws, size_t ws_size,
                              hipStream_t stream) {
    const float* x  = (const float*)d_in[0];
    const float* V0 = (const float*)d_in[1];
    const float* V1 = (const float*)d_in[3];
    const float* V2 = (const float*)d_in[5];

    char* ws = (char*)d_ws;
    u16* xb   = (u16*)(ws);                          // 8 MB  (4096x1024)
    u16* V0b  = (u16*)(ws + ((size_t)8 << 20));      // 4 MB  (1024x2048, row-major)
    u16* V1t  = (u16*)(ws + ((size_t)12 << 20));     // 8 MB  (2048x2048, = V1^T)
    u16* V2t  = (u16*)(ws + ((size_t)20 << 20));     // 4 MB  (1024x2048, = V2^T)
    u16* P1   = (u16*)(ws + ((size_t)24 << 20));     // 4 MB  (1024x2048)
    u16* P2t  = (u16*)(ws + ((size_t)28 << 20));     // 2 MB  (1024x1024)
    u16* part = (u16*)(ws + ((size_t)30 << 20));     // 16 MB max (split-K partials)

    prep_convert<<<3072, 256, 0, stream>>>(x, xb, V0, V0b);
    prep_transpose<<<1536, 256, 0, stream>>>(V1, V1t, V2, V2t);

    // P1 = V0 @ V1 : M=1024, N=2048, K=2048, split-K 4x512
    gemm_bt<<<dim3(16, 8, 4), 512, 0, stream>>>(V0b, V1t, part, 1024, 2048, 2048, 512);
    reduce_parts<4, 0><<<1024, 256, 0, stream>>>(part, P1, 1024 * 2048);

    // P2t = V2^T @ P1^T : M=1024, N=1024, K=2048, split-K 8x256
    gemm_bt<<<dim3(8, 8, 8), 512, 0, stream>>>(V2t, P1, part, 1024, 1024, 2048, 256);
    reduce_parts<8, 0><<<512, 256, 0, stream>>>(part, P2t, 1024 * 1024);

    // G = x @ P2 : M=4096, N=1024, K=1024, split-K 2x512
    gemm_bt<<<dim3(8, 32, 2), 512, 0, stream>>>(xb, P2t, part, 4096, 1024, 1024, 512);
    reduce_parts<2, 1><<<2048, 256, 0, stream>>>(part, d_out, 4096 * 1024);
}